// Round 7
// baseline (306.865 us; speedup 1.0000x reference)
//
#include <hip/hip_runtime.h>
#include <hip/hip_cooperative_groups.h>

namespace cg = cooperative_groups;

#define MOM 0.9f
#define ONE_MINUS_MOM 0.1f
#define MAXK 16
#define GRID_BLOCKS 1024

// One cooperative kernel, three phases separated by grid syncs:
//  A: zero cnt; per-row argmax of scores (first-max tie-break == np.argmax),
//     key[i] = (label<<1) | (pred != label)
//  B: rank: one wave per sample; ballot sweep gives e (# earlier chosen, same
//     label) and c (# later). slot[l*MAXK+e]=i; e==0 wave writes cnt[l]=c+1.
//  C: update: one wave per class (grid-stride):
//     out = m^k * bank + sum_p 0.1*m^(k-1-p) * feat[j_p]; out_times = times+k.
__global__ __launch_bounds__(256, 4) void fused_all_kernel(
    const float* __restrict__ scores, const int* __restrict__ labels,
    const float* __restrict__ feat, const float* __restrict__ bank,
    const float* __restrict__ times,
    int* __restrict__ key, int* __restrict__ cnt, int* __restrict__ slot,
    float* __restrict__ out_bank, float* __restrict__ out_times,
    int B, int C, int D)
{
    cg::grid_group grid = cg::this_grid();
    const int tid  = threadIdx.x;
    const int lane = tid & 63;
    const int wid  = tid >> 6;
    const int nblk = gridDim.x;

    __shared__ float sv[4];
    __shared__ int   si[4];

    // ---------------- Phase A: cnt zero + argmax ----------------
    for (int l = blockIdx.x * 256 + tid; l < C; l += nblk * 256) cnt[l] = 0;

    const int nvC = C >> 2;
    for (int row = blockIdx.x; row < B; row += nblk) {
        const float* rp = scores + (size_t)row * C;
        const float4* r4 = (const float4*)rp;

        // 4 independent (value, float4-index) chains
        float b0 = -__builtin_inff(), b1 = b0, b2 = b0, b3 = b0;
        int v0 = 0x7fffffff, v1 = v0, v2 = v0, v3 = v0;
        for (int v = tid; v < nvC; v += 256) {
            float4 s = r4[v];
            if (s.x > b0) { b0 = s.x; v0 = v; }
            if (s.y > b1) { b1 = s.y; v1 = v; }
            if (s.z > b2) { b2 = s.z; v2 = v; }
            if (s.w > b3) { b3 = s.w; v3 = v; }
        }
        // merge: value desc, overall index asc (np.argmax first-max)
        float best = b0; int bidx = (v0 << 2) | 0;
        { int oi = (v1 << 2) | 1; if (b1 > best || (b1 == best && oi < bidx)) { best = b1; bidx = oi; } }
        { int oi = (v2 << 2) | 2; if (b2 > best || (b2 == best && oi < bidx)) { best = b2; bidx = oi; } }
        { int oi = (v3 << 2) | 3; if (b3 > best || (b3 == best && oi < bidx)) { best = b3; bidx = oi; } }
        for (int c = (nvC << 2) + tid; c < C; c += 256) {
            float s = rp[c];
            if (s > best) { best = s; bidx = c; }
        }

        #pragma unroll
        for (int off = 32; off > 0; off >>= 1) {
            float ov = __shfl_xor(best, off);
            int   oi = __shfl_xor(bidx, off);
            if (ov > best || (ov == best && oi < bidx)) { best = ov; bidx = oi; }
        }

        if (lane == 0) { sv[wid] = best; si[wid] = bidx; }
        __syncthreads();
        if (tid == 0) {
            float bv = sv[0]; int bi = si[0];
            #pragma unroll
            for (int w = 1; w < 4; ++w) {
                float ov = sv[w]; int oi = si[w];
                if (ov > bv || (ov == bv && oi < bi)) { bv = ov; bi = oi; }
            }
            int lab = labels[row];
            key[row] = (lab << 1) | ((bi != lab) ? 1 : 0);
        }
        __syncthreads();   // protect sv/si reuse next row
    }

    grid.sync();

    // ---------------- Phase B: rank (one wave per sample) ----------------
    const int gw = blockIdx.x * 4 + wid;       // global wave id
    const int nw = nblk * 4;
    for (int i = gw; i < B; i += nw) {
        const int mykey = key[i];
        if (!(mykey & 1)) continue;
        int e = 0, c = 0;
        for (int base = 0; base < B; base += 64) {
            int j = base + lane;
            int kj = (j < B) ? key[j] : -1;
            bool match = (kj == mykey);
            e += __popcll(__ballot(match && (j < i)));
            c += __popcll(__ballot(match && (j > i)));
        }
        if (lane == 0) {
            int l = mykey >> 1;
            if (e < MAXK) slot[l * MAXK + e] = i;
            if (e == 0) cnt[l] = c + 1;
        }
    }

    grid.sync();

    // ---------------- Phase C: per-class update ----------------
    const int nvD = D >> 2;
    for (int l = gw; l < C; l += nw) {
        const int k = cnt[l];
        const int kk = (k < MAXK) ? k : MAXK;
        float scale = 1.0f;
        const int kc = (k < 128) ? k : 128;    // 0.9^128 ~ 1e-6: safe clamp
        for (int p = 0; p < kc; ++p) scale *= MOM;

        const float4* brow = (const float4*)(bank + (size_t)l * D);
        float4* orow = (float4*)(out_bank + (size_t)l * D);
        const int sbase = l * MAXK;

        if (nvD == 256) {
            float4 a0 = brow[lane];
            float4 a1 = brow[lane + 64];
            float4 a2 = brow[lane + 128];
            float4 a3 = brow[lane + 192];
            a0.x *= scale; a0.y *= scale; a0.z *= scale; a0.w *= scale;
            a1.x *= scale; a1.y *= scale; a1.z *= scale; a1.w *= scale;
            a2.x *= scale; a2.y *= scale; a2.z *= scale; a2.w *= scale;
            a3.x *= scale; a3.y *= scale; a3.z *= scale; a3.w *= scale;
            float wgt = ONE_MINUS_MOM;
            for (int r = kk - 1; r >= 0; --r) {
                int j = slot[sbase + r];
                const float4* f4 = (const float4*)(feat + (size_t)j * D);
                float4 f0 = f4[lane];
                float4 f1 = f4[lane + 64];
                float4 f2 = f4[lane + 128];
                float4 f3 = f4[lane + 192];
                a0.x += wgt * f0.x; a0.y += wgt * f0.y; a0.z += wgt * f0.z; a0.w += wgt * f0.w;
                a1.x += wgt * f1.x; a1.y += wgt * f1.y; a1.z += wgt * f1.z; a1.w += wgt * f1.w;
                a2.x += wgt * f2.x; a2.y += wgt * f2.y; a2.z += wgt * f2.z; a2.w += wgt * f2.w;
                a3.x += wgt * f3.x; a3.y += wgt * f3.y; a3.z += wgt * f3.z; a3.w += wgt * f3.w;
                wgt *= MOM;
            }
            orow[lane] = a0;
            orow[lane + 64] = a1;
            orow[lane + 128] = a2;
            orow[lane + 192] = a3;
        } else {
            for (int v = lane; v < nvD; v += 64) {
                float4 a = brow[v];
                a.x *= scale; a.y *= scale; a.z *= scale; a.w *= scale;
                float wgt = ONE_MINUS_MOM;
                for (int r = kk - 1; r >= 0; --r) {
                    int j = slot[sbase + r];
                    const float4* f4 = (const float4*)(feat + (size_t)j * D);
                    float4 f = f4[v];
                    a.x += wgt * f.x; a.y += wgt * f.y; a.z += wgt * f.z; a.w += wgt * f.w;
                    wgt *= MOM;
                }
                orow[v] = a;
            }
        }
        if (lane == 0) out_times[l] = times[l] + (float)k;
    }
}

extern "C" void kernel_launch(void* const* d_in, const int* in_sizes, int n_in,
                              void* d_out, int out_size, void* d_ws, size_t ws_size,
                              hipStream_t stream) {
    const float* scores = (const float*)d_in[0];
    const float* feat   = (const float*)d_in[1];
    const float* bank   = (const float*)d_in[2];
    const float* times  = (const float*)d_in[3];
    const int*   labels = (const int*)d_in[4];

    int B = in_sizes[4];            // 4096
    int C = in_sizes[3];            // 10000
    int D = in_sizes[1] / B;        // 1024

    float* out_bank  = (float*)d_out;
    float* out_times = out_bank + (size_t)C * D;

    int* key  = (int*)d_ws;               // B
    int* cnt  = key + B;                  // C
    int* slot = cnt + C;                  // C * MAXK

    void* args[] = {
        (void*)&scores, (void*)&labels, (void*)&feat, (void*)&bank,
        (void*)&times, (void*)&key, (void*)&cnt, (void*)&slot,
        (void*)&out_bank, (void*)&out_times,
        (void*)&B, (void*)&C, (void*)&D
    };
    hipLaunchCooperativeKernel((void*)fused_all_kernel,
                               dim3(GRID_BLOCKS), dim3(256),
                               args, 0, stream);
}

// Round 8
// 63.719 us; speedup vs baseline: 4.8159x; 4.8159x over previous
//
#include <hip/hip_runtime.h>

#define MOM 0.9f
#define ONE_MINUS_MOM 0.1f
#define MAXK 16

typedef float f32x4 __attribute__((ext_vector_type(4)));

__device__ __forceinline__ f32x4 ntload4(const float* p) {
    return __builtin_nontemporal_load((const f32x4*)p);
}
__device__ __forceinline__ void ntstore4(float* p, f32x4 v) {
    __builtin_nontemporal_store(v, (f32x4*)p);
}

// K1: per-row argmax of scores (first-max tie-break, matching np.argmax),
// emit key[i] = (label << 1) | (pred != label). Also zeroes cnt[] (visible
// to K2 via stream ordering). Non-temporal loads: scores are single-touch.
__global__ __launch_bounds__(256) void argmax_key_kernel(
    const float* __restrict__ scores, const int* __restrict__ labels,
    int* __restrict__ key, int* __restrict__ cnt, int C)
{
    // fold cnt zeroing into the grid (4 per block; B blocks * 4 >= C)
    if (threadIdx.x < 4) {
        int l = ((int)blockIdx.x << 2) | (int)threadIdx.x;
        if (l < C) cnt[l] = 0;
    }

    const int row = blockIdx.x;
    const float* rp = scores + (size_t)row * C;
    const int nv = C >> 2;

    // 4 independent (value, float4-index) chains; unroll-4 => up to 4
    // independent 16B loads in flight per thread before any compare retires.
    float b0 = -__builtin_inff(), b1 = b0, b2 = b0, b3 = b0;
    int v0 = 0x7fffffff, v1 = v0, v2 = v0, v3 = v0;
    #pragma unroll 4
    for (int v = threadIdx.x; v < nv; v += 256) {
        f32x4 s = ntload4(rp + (v << 2));
        if (s.x > b0) { b0 = s.x; v0 = v; }
        if (s.y > b1) { b1 = s.y; v1 = v; }
        if (s.z > b2) { b2 = s.z; v2 = v; }
        if (s.w > b3) { b3 = s.w; v3 = v; }
    }
    // merge chains: value desc, overall index asc (np.argmax first-max)
    float best = b0; int bidx = (v0 << 2) | 0;
    { int oi = (v1 << 2) | 1; if (b1 > best || (b1 == best && oi < bidx)) { best = b1; bidx = oi; } }
    { int oi = (v2 << 2) | 2; if (b2 > best || (b2 == best && oi < bidx)) { best = b2; bidx = oi; } }
    { int oi = (v3 << 2) | 3; if (b3 > best || (b3 == best && oi < bidx)) { best = b3; bidx = oi; } }
    for (int c = (nv << 2) + threadIdx.x; c < C; c += 256) {
        float s = rp[c];
        if (s > best) { best = s; bidx = c; }
    }

    // in-wave butterfly reduce (value desc, index asc tie-break)
    #pragma unroll
    for (int off = 32; off > 0; off >>= 1) {
        float ov = __shfl_xor(best, off);
        int   oi = __shfl_xor(bidx, off);
        if (ov > best || (ov == best && oi < bidx)) { best = ov; bidx = oi; }
    }

    __shared__ float sv[4];
    __shared__ int   si[4];
    const int lane = threadIdx.x & 63;
    const int wid  = threadIdx.x >> 6;
    if (lane == 0) { sv[wid] = best; si[wid] = bidx; }
    __syncthreads();
    if (threadIdx.x == 0) {
        float bv = sv[0]; int bi = si[0];
        #pragma unroll
        for (int w = 1; w < 4; ++w) {
            float ov = sv[w]; int oi = si[w];
            if (ov > bv || (ov == bv && oi < bi)) { bv = ov; bi = oi; }
        }
        int lab = labels[row];
        key[row] = (lab << 1) | ((bi != lab) ? 1 : 0);
    }
}

// K2: one wave per sample i. One ballot sweep over key[] (16 KB, L2-hot)
// yields e = # earlier chosen same-label and c = # later. Chosen sample i
// goes to slot[class*MAXK + e]; the unique e==0 sample writes cnt[l] = c+1.
// Deterministic, no atomics.
__global__ __launch_bounds__(256) void rank_kernel(
    const int* __restrict__ key, int* __restrict__ cnt,
    int* __restrict__ slot, int B)
{
    const int lane = threadIdx.x & 63;
    const int i = blockIdx.x * 4 + (threadIdx.x >> 6);
    if (i >= B) return;
    const int mykey = key[i];
    if (!(mykey & 1)) return;   // not chosen

    int e = 0, c = 0;
    for (int base = 0; base < B; base += 64) {
        int j = base + lane;
        int kj = (j < B) ? key[j] : -1;
        bool match = (kj == mykey);
        e += __popcll(__ballot(match && (j < i)));
        c += __popcll(__ballot(match && (j > i)));
    }
    if (lane == 0) {
        int l = mykey >> 1;
        if (e < MAXK) slot[l * MAXK + e] = i;
        if (e == 0) cnt[l] = c + 1;
    }
}

// K3: one WAVE per class (4/block). Bank-row loads are issued FIRST (in
// flight while cnt/slot resolve). k=0 classes (~2/3) take a pure streaming
// copy path. Non-temporal on bank/feat/out (all single-touch).
// out = m^k * bank + sum_r w_r * feat[slot_r], ranks descending so the
// weight is a running multiply. No barriers.
__global__ __launch_bounds__(256) void update_kernel(
    const float* __restrict__ bank, const float* __restrict__ times,
    const float* __restrict__ feat, const int* __restrict__ cnt,
    const int* __restrict__ slot,
    float* __restrict__ out_bank, float* __restrict__ out_times, int C, int D)
{
    const int lane = threadIdx.x & 63;
    const int wid  = threadIdx.x >> 6;
    const int l = (blockIdx.x << 2) | wid;
    if (l >= C) return;

    const float* brow = bank + (size_t)l * D;
    float* orow = out_bank + (size_t)l * D;
    const int nv = D >> 2;

    if (nv == 256) {
        // issue the 4 independent 1KB wave-loads immediately
        f32x4 a0 = ntload4(brow + (lane << 2));
        f32x4 a1 = ntload4(brow + ((lane + 64) << 2));
        f32x4 a2 = ntload4(brow + ((lane + 128) << 2));
        f32x4 a3 = ntload4(brow + ((lane + 192) << 2));
        const float tl = times[l];
        const int k = cnt[l];

        if (k == 0) {
            ntstore4(orow + (lane << 2), a0);
            ntstore4(orow + ((lane + 64) << 2), a1);
            ntstore4(orow + ((lane + 128) << 2), a2);
            ntstore4(orow + ((lane + 192) << 2), a3);
            if (lane == 0) out_times[l] = tl;
            return;
        }

        const int kk = (k < MAXK) ? k : MAXK;
        float scale = 1.0f;
        const int kc = (k < 128) ? k : 128;   // 0.9^128 ~ 1e-6: safe clamp
        for (int p = 0; p < kc; ++p) scale *= MOM;

        a0 *= scale; a1 *= scale; a2 *= scale; a3 *= scale;

        const int sbase = l * MAXK;
        float wgt = ONE_MINUS_MOM;
        for (int r = kk - 1; r >= 0; --r) {
            int j = slot[sbase + r];   // same address all lanes -> broadcast
            const float* frow = feat + (size_t)j * D;
            f32x4 f0 = ntload4(frow + (lane << 2));
            f32x4 f1 = ntload4(frow + ((lane + 64) << 2));
            f32x4 f2 = ntload4(frow + ((lane + 128) << 2));
            f32x4 f3 = ntload4(frow + ((lane + 192) << 2));
            a0 += wgt * f0;
            a1 += wgt * f1;
            a2 += wgt * f2;
            a3 += wgt * f3;
            wgt *= MOM;
        }
        ntstore4(orow + (lane << 2), a0);
        ntstore4(orow + ((lane + 64) << 2), a1);
        ntstore4(orow + ((lane + 128) << 2), a2);
        ntstore4(orow + ((lane + 192) << 2), a3);
        if (lane == 0) out_times[l] = tl + (float)k;
    } else {
        // generic-D fallback
        const float tl = times[l];
        const int k = cnt[l];
        const int kk = (k < MAXK) ? k : MAXK;
        float scale = 1.0f;
        const int kc = (k < 128) ? k : 128;
        for (int p = 0; p < kc; ++p) scale *= MOM;
        const int sbase = l * MAXK;
        for (int v = lane; v < nv; v += 64) {
            f32x4 a = ntload4(brow + (v << 2));
            a *= scale;
            float wgt = ONE_MINUS_MOM;
            for (int r = kk - 1; r >= 0; --r) {
                int j = slot[sbase + r];
                f32x4 f = ntload4(feat + (size_t)j * D + (v << 2));
                a += wgt * f;
                wgt *= MOM;
            }
            ntstore4(orow + (v << 2), a);
        }
        if (lane == 0) out_times[l] = tl + (float)k;
    }
}

extern "C" void kernel_launch(void* const* d_in, const int* in_sizes, int n_in,
                              void* d_out, int out_size, void* d_ws, size_t ws_size,
                              hipStream_t stream) {
    const float* scores = (const float*)d_in[0];
    const float* feat   = (const float*)d_in[1];
    const float* bank   = (const float*)d_in[2];
    const float* times  = (const float*)d_in[3];
    const int*   labels = (const int*)d_in[4];

    const int B = in_sizes[4];            // 4096
    const int C = in_sizes[3];            // 10000
    const int D = in_sizes[1] / B;        // 1024

    float* out_bank  = (float*)d_out;
    float* out_times = out_bank + (size_t)C * D;

    int* key  = (int*)d_ws;               // B
    int* cnt  = key + B;                  // C
    int* slot = cnt + C;                  // C * MAXK

    argmax_key_kernel<<<B, 256, 0, stream>>>(scores, labels, key, cnt, C);
    rank_kernel<<<(B + 3) / 4, 256, 0, stream>>>(key, cnt, slot, B);
    update_kernel<<<(C + 3) / 4, 256, 0, stream>>>(bank, times, feat, cnt, slot,
                                                   out_bank, out_times, C, D);
}

// Round 9
// 55.597 us; speedup vs baseline: 5.5194x; 1.1461x over previous
//
#include <hip/hip_runtime.h>

#define MOM 0.9f
#define ONE_MINUS_MOM 0.1f
#define MAXK 16

typedef float f32x4 __attribute__((ext_vector_type(4)));

// K1: per-row argmax of scores (first-max tie-break, matching np.argmax).
// If pred != label, scatter the sample directly into its class's slot list
// via atomicAdd (unordered; K3 re-establishes order by sorting indices).
__global__ __launch_bounds__(256) void argmax_scatter_kernel(
    const float* __restrict__ scores, const int* __restrict__ labels,
    int* __restrict__ cnt, int* __restrict__ slot, int C)
{
    const int row = blockIdx.x;
    const float* rp = scores + (size_t)row * C;
    const int nv = C >> 2;
    const float4* r4 = (const float4*)rp;

    // 4 independent (value, float4-index) chains
    float b0 = -__builtin_inff(), b1 = b0, b2 = b0, b3 = b0;
    int v0 = 0x7fffffff, v1 = v0, v2 = v0, v3 = v0;
    for (int v = threadIdx.x; v < nv; v += 256) {
        float4 s = r4[v];
        if (s.x > b0) { b0 = s.x; v0 = v; }
        if (s.y > b1) { b1 = s.y; v1 = v; }
        if (s.z > b2) { b2 = s.z; v2 = v; }
        if (s.w > b3) { b3 = s.w; v3 = v; }
    }
    // merge chains: value desc, overall index asc (np.argmax first-max)
    float best = b0; int bidx = (v0 << 2) | 0;
    { int oi = (v1 << 2) | 1; if (b1 > best || (b1 == best && oi < bidx)) { best = b1; bidx = oi; } }
    { int oi = (v2 << 2) | 2; if (b2 > best || (b2 == best && oi < bidx)) { best = b2; bidx = oi; } }
    { int oi = (v3 << 2) | 3; if (b3 > best || (b3 == best && oi < bidx)) { best = b3; bidx = oi; } }
    for (int c = (nv << 2) + threadIdx.x; c < C; c += 256) {
        float s = rp[c];
        if (s > best) { best = s; bidx = c; }
    }

    // in-wave butterfly reduce (value desc, index asc tie-break)
    #pragma unroll
    for (int off = 32; off > 0; off >>= 1) {
        float ov = __shfl_xor(best, off);
        int   oi = __shfl_xor(bidx, off);
        if (ov > best || (ov == best && oi < bidx)) { best = ov; bidx = oi; }
    }

    __shared__ float sv[4];
    __shared__ int   si[4];
    const int lane = threadIdx.x & 63;
    const int wid  = threadIdx.x >> 6;
    if (lane == 0) { sv[wid] = best; si[wid] = bidx; }
    __syncthreads();
    if (threadIdx.x == 0) {
        float bv = sv[0]; int bi = si[0];
        #pragma unroll
        for (int w = 1; w < 4; ++w) {
            float ov = sv[w]; int oi = si[w];
            if (ov > bv || (ov == bv && oi < bi)) { bv = ov; bi = oi; }
        }
        int lab = labels[row];
        if (bi != lab) {
            int pos = atomicAdd(&cnt[lab], 1);   // device-scope, cross-XCD safe
            if (pos < MAXK) slot[lab * MAXK + pos] = row;
        }
    }
}

// K3: one WAVE per class (4/block). Bank loads issued first (in flight while
// cnt/slot resolve). Selection-sorts its <=kk slot entries ascending on the
// fly (kk^2 <= 256 L1-hot uniform scalar loads, no register arrays), applies
// exact weights 0.1*0.9^(k-1-s) in deterministic ascending-index order:
//   out = m^k * bank + sum_s w_s * feat[j_s];  out_times = times + k.
// No LDS, no barriers.
__global__ __launch_bounds__(256) void update_kernel(
    const float* __restrict__ bank, const float* __restrict__ times,
    const float* __restrict__ feat, const int* __restrict__ cnt,
    const int* __restrict__ slot,
    float* __restrict__ out_bank, float* __restrict__ out_times, int C, int D)
{
    const int lane = threadIdx.x & 63;
    const int wid  = threadIdx.x >> 6;
    const int l = (blockIdx.x << 2) | wid;
    if (l >= C) return;

    const float4* brow = (const float4*)(bank + (size_t)l * D);
    float4* orow = (float4*)(out_bank + (size_t)l * D);
    const int nv = D >> 2;
    const int sbase = l * MAXK;

    if (nv == 256) {
        // issue the 4 independent 1KB wave-loads immediately
        float4 a0 = brow[lane];
        float4 a1 = brow[lane + 64];
        float4 a2 = brow[lane + 128];
        float4 a3 = brow[lane + 192];
        const float tl = times[l];
        const int k = cnt[l];
        const int kk = (k < MAXK) ? k : MAXK;

        float scale = 1.0f;
        const int kc = (k < 128) ? k : 128;   // 0.9^128 ~ 1e-6: safe clamp
        for (int p = 0; p < kc; ++p) scale *= MOM;
        a0.x *= scale; a0.y *= scale; a0.z *= scale; a0.w *= scale;
        a1.x *= scale; a1.y *= scale; a1.z *= scale; a1.w *= scale;
        a2.x *= scale; a2.y *= scale; a2.z *= scale; a2.w *= scale;
        a3.x *= scale; a3.y *= scale; a3.z *= scale; a3.w *= scale;

        int last = -1;
        for (int s = 0; s < kk; ++s) {
            // select next-smallest sample index (uniform across lanes)
            int cur = 0x7fffffff;
            for (int p = 0; p < kk; ++p) {
                int j = slot[sbase + p];
                if (j > last && j < cur) cur = j;
            }
            int e = k - 1 - s; if (e > 127) e = 127;
            float w = ONE_MINUS_MOM;
            for (int t = 0; t < e; ++t) w *= MOM;

            const float4* f4 = (const float4*)(feat + (size_t)cur * D);
            float4 f0 = f4[lane];
            float4 f1 = f4[lane + 64];
            float4 f2 = f4[lane + 128];
            float4 f3 = f4[lane + 192];
            a0.x += w * f0.x; a0.y += w * f0.y; a0.z += w * f0.z; a0.w += w * f0.w;
            a1.x += w * f1.x; a1.y += w * f1.y; a1.z += w * f1.z; a1.w += w * f1.w;
            a2.x += w * f2.x; a2.y += w * f2.y; a2.z += w * f2.z; a2.w += w * f2.w;
            a3.x += w * f3.x; a3.y += w * f3.y; a3.z += w * f3.z; a3.w += w * f3.w;
            last = cur;
        }
        orow[lane] = a0;
        orow[lane + 64] = a1;
        orow[lane + 128] = a2;
        orow[lane + 192] = a3;
        if (lane == 0) out_times[l] = tl + (float)k;
    } else {
        // generic-D fallback
        const float tl = times[l];
        const int k = cnt[l];
        const int kk = (k < MAXK) ? k : MAXK;
        float scale = 1.0f;
        const int kc = (k < 128) ? k : 128;
        for (int p = 0; p < kc; ++p) scale *= MOM;
        for (int v = lane; v < nv; v += 64) {
            float4 a = brow[v];
            a.x *= scale; a.y *= scale; a.z *= scale; a.w *= scale;
            int last = -1;
            for (int s = 0; s < kk; ++s) {
                int cur = 0x7fffffff;
                for (int p = 0; p < kk; ++p) {
                    int j = slot[sbase + p];
                    if (j > last && j < cur) cur = j;
                }
                int e = k - 1 - s; if (e > 127) e = 127;
                float w = ONE_MINUS_MOM;
                for (int t = 0; t < e; ++t) w *= MOM;
                const float4* f4 = (const float4*)(feat + (size_t)cur * D);
                float4 f = f4[v];
                a.x += w * f.x; a.y += w * f.y; a.z += w * f.z; a.w += w * f.w;
                last = cur;
            }
            orow[v] = a;
        }
        if (lane == 0) out_times[l] = tl + (float)k;
    }
}

extern "C" void kernel_launch(void* const* d_in, const int* in_sizes, int n_in,
                              void* d_out, int out_size, void* d_ws, size_t ws_size,
                              hipStream_t stream) {
    const float* scores = (const float*)d_in[0];
    const float* feat   = (const float*)d_in[1];
    const float* bank   = (const float*)d_in[2];
    const float* times  = (const float*)d_in[3];
    const int*   labels = (const int*)d_in[4];

    const int B = in_sizes[4];            // 4096
    const int C = in_sizes[3];            // 10000
    const int D = in_sizes[1] / B;        // 1024

    float* out_bank  = (float*)d_out;
    float* out_times = out_bank + (size_t)C * D;

    int* cnt  = (int*)d_ws;               // C
    int* slot = cnt + C;                  // C * MAXK

    hipMemsetAsync(cnt, 0, (size_t)C * sizeof(int), stream);
    argmax_scatter_kernel<<<B, 256, 0, stream>>>(scores, labels, cnt, slot, C);
    update_kernel<<<(C + 3) / 4, 256, 0, stream>>>(bank, times, feat, cnt, slot,
                                                   out_bank, out_times, C, D);
}

// Round 10
// 50.650 us; speedup vs baseline: 6.0586x; 1.0977x over previous
//
#include <hip/hip_runtime.h>

#define MOM 0.9f
#define ONE_MINUS_MOM 0.1f
#define MAXK 16

// K1: per-row argmax of scores (first-max tie-break, matching np.argmax),
// emit key[i] = (label << 1) | (pred != label). No atomics, no side buffers.
__global__ __launch_bounds__(256) void argmax_key_kernel(
    const float* __restrict__ scores, const int* __restrict__ labels,
    int* __restrict__ key, int C)
{
    const int row = blockIdx.x;
    const float* rp = scores + (size_t)row * C;
    const int nv = C >> 2;
    const float4* r4 = (const float4*)rp;

    // 4 independent (value, float4-index) chains
    float b0 = -__builtin_inff(), b1 = b0, b2 = b0, b3 = b0;
    int v0 = 0x7fffffff, v1 = v0, v2 = v0, v3 = v0;
    for (int v = threadIdx.x; v < nv; v += 256) {
        float4 s = r4[v];
        if (s.x > b0) { b0 = s.x; v0 = v; }
        if (s.y > b1) { b1 = s.y; v1 = v; }
        if (s.z > b2) { b2 = s.z; v2 = v; }
        if (s.w > b3) { b3 = s.w; v3 = v; }
    }
    // merge chains: value desc, overall index asc (np.argmax first-max)
    float best = b0; int bidx = (v0 << 2) | 0;
    { int oi = (v1 << 2) | 1; if (b1 > best || (b1 == best && oi < bidx)) { best = b1; bidx = oi; } }
    { int oi = (v2 << 2) | 2; if (b2 > best || (b2 == best && oi < bidx)) { best = b2; bidx = oi; } }
    { int oi = (v3 << 2) | 3; if (b3 > best || (b3 == best && oi < bidx)) { best = b3; bidx = oi; } }
    for (int c = (nv << 2) + threadIdx.x; c < C; c += 256) {
        float s = rp[c];
        if (s > best) { best = s; bidx = c; }
    }

    // in-wave butterfly reduce (value desc, index asc tie-break)
    #pragma unroll
    for (int off = 32; off > 0; off >>= 1) {
        float ov = __shfl_xor(best, off);
        int   oi = __shfl_xor(bidx, off);
        if (ov > best || (ov == best && oi < bidx)) { best = ov; bidx = oi; }
    }

    __shared__ float sv[4];
    __shared__ int   si[4];
    const int lane = threadIdx.x & 63;
    const int wid  = threadIdx.x >> 6;
    if (lane == 0) { sv[wid] = best; si[wid] = bidx; }
    __syncthreads();
    if (threadIdx.x == 0) {
        float bv = sv[0]; int bi = si[0];
        #pragma unroll
        for (int w = 1; w < 4; ++w) {
            float ov = sv[w]; int oi = si[w];
            if (ov > bv || (ov == bv && oi < bi)) { bv = ov; bi = oi; }
        }
        int lab = labels[row];
        key[row] = (lab << 1) | ((bi != lab) ? 1 : 0);
    }
}

// K2: one block per 4 classes (wave w owns class l = blk*4+w).
//  (a) each wave issues its bank-row loads (stay in flight through the scan),
//  (b) 256 threads block-cooperatively scan key[] as int4 (L2-hot); chosen
//      samples whose class lands in this block go to a per-class LDS list
//      via LDS atomicAdd (unordered; expected ~1.6 matches/block),
//  (c) selection-sort (<=k^2 LDS broadcast reads) makes the order canonical
//      ascending; weights 0.1*0.9^(k-1-s); out = m^k*bank + sum w_s*feat[j_s],
//  (d) out_times = times + k.
__global__ __launch_bounds__(256) void update_kernel(
    const float* __restrict__ bank, const float* __restrict__ times,
    const float* __restrict__ feat, const int* __restrict__ key,
    float* __restrict__ out_bank, float* __restrict__ out_times,
    int B, int C, int D)
{
    const int tid  = threadIdx.x;
    const int lane = tid & 63;
    const int wid  = tid >> 6;
    const int lbase = (int)blockIdx.x << 2;
    const int l = lbase | wid;

    __shared__ int scnt[4];
    __shared__ int list[4][MAXK];

    const bool valid = (l < C);
    const float4* brow = valid ? (const float4*)(bank + (size_t)l * D) : nullptr;
    float4* orow = valid ? (float4*)(out_bank + (size_t)l * D) : nullptr;
    const int nv = D >> 2;

    // (a) issue bank loads first (fast path D=1024)
    float4 a0, a1, a2, a3;
    float tl = 0.0f;
    const bool fast = (nv == 256) && valid;
    if (fast) {
        a0 = brow[lane];
        a1 = brow[lane + 64];
        a2 = brow[lane + 128];
        a3 = brow[lane + 192];
        tl = times[l];
    }

    if (tid < 4) scnt[tid] = 0;
    __syncthreads();

    // (b) block-cooperative key scan
    const int nk4 = B >> 2;
    const int4* k4 = (const int4*)key;
    for (int q = tid; q < nk4; q += 256) {
        int4 kv = k4[q];
        int j0 = q << 2;
        int c0 = (kv.x >> 1) - lbase;
        if ((kv.x & 1) && (unsigned)c0 < 4u) {
            int pos = atomicAdd(&scnt[c0], 1);
            if (pos < MAXK) list[c0][pos] = j0;
        }
        int c1 = (kv.y >> 1) - lbase;
        if ((kv.y & 1) && (unsigned)c1 < 4u) {
            int pos = atomicAdd(&scnt[c1], 1);
            if (pos < MAXK) list[c1][pos] = j0 + 1;
        }
        int c2 = (kv.z >> 1) - lbase;
        if ((kv.z & 1) && (unsigned)c2 < 4u) {
            int pos = atomicAdd(&scnt[c2], 1);
            if (pos < MAXK) list[c2][pos] = j0 + 2;
        }
        int c3 = (kv.w >> 1) - lbase;
        if ((kv.w & 1) && (unsigned)c3 < 4u) {
            int pos = atomicAdd(&scnt[c3], 1);
            if (pos < MAXK) list[c3][pos] = j0 + 3;
        }
    }
    for (int j = (nk4 << 2) + tid; j < B; j += 256) {   // tail if B%4
        int kj = key[j];
        int c = (kj >> 1) - lbase;
        if ((kj & 1) && (unsigned)c < 4u) {
            int pos = atomicAdd(&scnt[c], 1);
            if (pos < MAXK) list[c][pos] = j;
        }
    }
    __syncthreads();

    if (!valid) return;

    const int k = scnt[wid];
    const int kk = (k < MAXK) ? k : MAXK;

    float scale = 1.0f;
    const int kc = (k < 128) ? k : 128;   // 0.9^128 ~ 1e-6: safe clamp
    for (int p = 0; p < kc; ++p) scale *= MOM;

    if (fast) {
        a0.x *= scale; a0.y *= scale; a0.z *= scale; a0.w *= scale;
        a1.x *= scale; a1.y *= scale; a1.z *= scale; a1.w *= scale;
        a2.x *= scale; a2.y *= scale; a2.z *= scale; a2.w *= scale;
        a3.x *= scale; a3.y *= scale; a3.z *= scale; a3.w *= scale;

        int last = -1;
        for (int s = 0; s < kk; ++s) {
            // (c) next-smallest sample index (uniform LDS broadcast reads)
            int cur = 0x7fffffff;
            for (int p = 0; p < kk; ++p) {
                int j = list[wid][p];
                if (j > last && j < cur) cur = j;
            }
            int e = k - 1 - s; if (e > 127) e = 127;
            float w = ONE_MINUS_MOM;
            for (int t = 0; t < e; ++t) w *= MOM;

            const float4* f4 = (const float4*)(feat + (size_t)cur * D);
            float4 f0 = f4[lane];
            float4 f1 = f4[lane + 64];
            float4 f2 = f4[lane + 128];
            float4 f3 = f4[lane + 192];
            a0.x += w * f0.x; a0.y += w * f0.y; a0.z += w * f0.z; a0.w += w * f0.w;
            a1.x += w * f1.x; a1.y += w * f1.y; a1.z += w * f1.z; a1.w += w * f1.w;
            a2.x += w * f2.x; a2.y += w * f2.y; a2.z += w * f2.z; a2.w += w * f2.w;
            a3.x += w * f3.x; a3.y += w * f3.y; a3.z += w * f3.z; a3.w += w * f3.w;
            last = cur;
        }
        orow[lane] = a0;
        orow[lane + 64] = a1;
        orow[lane + 128] = a2;
        orow[lane + 192] = a3;
        if (lane == 0) out_times[l] = tl + (float)k;
    } else {
        // generic-D fallback
        const float tlg = times[l];
        for (int v = lane; v < nv; v += 64) {
            float4 a = brow[v];
            a.x *= scale; a.y *= scale; a.z *= scale; a.w *= scale;
            int last = -1;
            for (int s = 0; s < kk; ++s) {
                int cur = 0x7fffffff;
                for (int p = 0; p < kk; ++p) {
                    int j = list[wid][p];
                    if (j > last && j < cur) cur = j;
                }
                int e = k - 1 - s; if (e > 127) e = 127;
                float w = ONE_MINUS_MOM;
                for (int t = 0; t < e; ++t) w *= MOM;
                const float4* f4 = (const float4*)(feat + (size_t)cur * D);
                float4 f = f4[v];
                a.x += w * f.x; a.y += w * f.y; a.z += w * f.z; a.w += w * f.w;
                last = cur;
            }
            orow[v] = a;
        }
        if (lane == 0) out_times[l] = tlg + (float)k;
    }
}

extern "C" void kernel_launch(void* const* d_in, const int* in_sizes, int n_in,
                              void* d_out, int out_size, void* d_ws, size_t ws_size,
                              hipStream_t stream) {
    const float* scores = (const float*)d_in[0];
    const float* feat   = (const float*)d_in[1];
    const float* bank   = (const float*)d_in[2];
    const float* times  = (const float*)d_in[3];
    const int*   labels = (const int*)d_in[4];

    const int B = in_sizes[4];            // 4096
    const int C = in_sizes[3];            // 10000
    const int D = in_sizes[1] / B;        // 1024

    float* out_bank  = (float*)d_out;
    float* out_times = out_bank + (size_t)C * D;

    int* key = (int*)d_ws;                // B ints

    argmax_key_kernel<<<B, 256, 0, stream>>>(scores, labels, key, C);
    update_kernel<<<(C + 3) / 4, 256, 0, stream>>>(bank, times, feat, key,
                                                   out_bank, out_times, B, C, D);
}